// Round 1
// baseline (267.747 us; speedup 1.0000x reference)
//
#include <hip/hip_runtime.h>
#include <math.h>

// Problem constants
#define BB   512   // batch
#define TT   256   // timesteps
#define CNNC 512   // channels
#define VV   37    // vocab
#define HH   8     // hidden
#define G4   32    // 4*H

// ---------------------------------------------------------------------------
// Kernel 1: adaptive-avg-pool(features) @ W_in.T + b_in  ->  feat[B][V]
// One block per batch element. Phase 1: per-channel spatial sums into LDS.
// Phase 2: 4 lanes per output v reduce the 512-dot.
// ---------------------------------------------------------------------------
__global__ __launch_bounds__(256) void k_feat(const float* __restrict__ features,
                                              const float* __restrict__ W_in,
                                              const float* __restrict__ b_in,
                                              float* __restrict__ feat) {
    __shared__ float pooled[CNNC];
    const int b = blockIdx.x;
    const int tid = threadIdx.x;
    const float* fb = features + (size_t)b * CNNC * 49;
    for (int c = tid; c < CNNC; c += 256) {
        const float* p = fb + c * 49;
        float s = 0.f;
        #pragma unroll
        for (int i = 0; i < 49; ++i) s += p[i];
        pooled[c] = s;
    }
    __syncthreads();
    const int v = tid >> 2, pp = tid & 3;
    if (v < VV) {
        const float* w = W_in + v * CNNC + pp * 128;
        const float* q = pooled + pp * 128;
        float s = 0.f;
        #pragma unroll 16
        for (int i = 0; i < 128; ++i) s += q[i] * w[i];
        s += __shfl_xor(s, 1);
        s += __shfl_xor(s, 2);
        if (pp == 0) feat[b * VV + v] = s * (1.f / 49.f) + b_in[v];
    }
}

// ---------------------------------------------------------------------------
// Kernel 2: xproj[b][t][g] = x_t[b] @ W_ih.T + (b_ih + b_hh)
//           x_0 = feat[b], x_t = captions[b][t-1]
// One block per b (t = threadIdx.x) -> caption reads are contiguous per wave,
// xproj writes are contiguous 8KB per wave. W_ih staged in LDS (broadcast).
// ---------------------------------------------------------------------------
__global__ __launch_bounds__(256) void k_xproj(const float* __restrict__ captions,
                                               const float* __restrict__ W_ih,
                                               const float* __restrict__ b_ih,
                                               const float* __restrict__ b_hh,
                                               const float* __restrict__ feat,
                                               float* __restrict__ xproj) {
    __shared__ float W[G4 * VV];
    __shared__ float bias[G4];
    const int b = blockIdx.x, t = threadIdx.x;
    for (int i = threadIdx.x; i < G4 * VV; i += 256) W[i] = W_ih[i];
    if (threadIdx.x < G4) bias[threadIdx.x] = b_ih[threadIdx.x] + b_hh[threadIdx.x];
    __syncthreads();

    const float* x = (t == 0) ? (feat + b * VV)
                              : (captions + ((size_t)b * TT + (t - 1)) * VV);
    float xr[VV];
    #pragma unroll
    for (int v = 0; v < VV; ++v) xr[v] = x[v];

    float acc[G4];
    #pragma unroll
    for (int g = 0; g < G4; ++g) acc[g] = bias[g];
    #pragma unroll
    for (int v = 0; v < VV; ++v) {
        const float xv = xr[v];
        #pragma unroll
        for (int g = 0; g < G4; ++g) acc[g] += xv * W[g * VV + v];
    }
    float* o = xproj + ((size_t)b * TT + t) * G4;
    #pragma unroll
    for (int g = 0; g < G4; ++g) o[g] = acc[g];
}

// ---------------------------------------------------------------------------
// Kernel 3: the sequential LSTM scan. 8 lanes per sequence; lane j owns
// hidden unit j and computes gates {i,f,g,o}[j] (4 x 8-FMA dots). h is
// broadcast within the 8-lane group by __shfl. Stores h_t to hbuf[b][t][8].
// 64 blocks x 64 threads -> 64 waves, one per CU; latency-bound.
// ---------------------------------------------------------------------------
__global__ __launch_bounds__(64) void k_lstm(const float* __restrict__ W_hh,
                                             const float* __restrict__ xproj,
                                             float* __restrict__ hbuf) {
    const int lane = threadIdx.x;
    const int j = lane & 7;
    const int b = blockIdx.x * 8 + (lane >> 3);
    const int base = lane & ~7;

    float wi[HH], wf[HH], wg[HH], wo[HH];
    #pragma unroll
    for (int k = 0; k < HH; ++k) {
        wi[k] = W_hh[(0 * HH + j) * HH + k];
        wf[k] = W_hh[(1 * HH + j) * HH + k];
        wg[k] = W_hh[(2 * HH + j) * HH + k];
        wo[k] = W_hh[(3 * HH + j) * HH + k];
    }
    const float* xp = xproj + (size_t)b * TT * G4;
    float* hp = hbuf + (size_t)b * TT * HH + j;

    float h = 0.f, c = 0.f;
    #pragma unroll 2
    for (int t = 0; t < TT; ++t) {
        const float* xq = xp + t * G4;
        float pi = xq[j];
        float pf = xq[HH + j];
        float pg = xq[2 * HH + j];
        float po = xq[3 * HH + j];

        float ha[HH];
        #pragma unroll
        for (int k = 0; k < HH; ++k) ha[k] = __shfl(h, base + k);
        #pragma unroll
        for (int k = 0; k < HH; ++k) {
            pi += wi[k] * ha[k];
            pf += wf[k] * ha[k];
            pg += wg[k] * ha[k];
            po += wo[k] * ha[k];
        }
        const float ig = 1.f / (1.f + __expf(-pi));
        const float fg = 1.f / (1.f + __expf(-pf));
        const float gg = 2.f / (1.f + __expf(-2.f * pg)) - 1.f;   // tanh
        const float og = 1.f / (1.f + __expf(-po));
        c = fg * c + ig * gg;
        const float th = 2.f / (1.f + __expf(-2.f * c)) - 1.f;     // tanh
        h = og * th;
        hp[t * HH] = h;
    }
}

// ---------------------------------------------------------------------------
// Kernel 4: out[b][t][:] = softmax(h_t @ W_out.T + b_out). One block per b,
// thread t handles row (b,t). Output staged in LDS, then written coalesced.
// This is the dominant dispatch: 194 MB of writes -> HBM-write-bound.
// ---------------------------------------------------------------------------
__global__ __launch_bounds__(256) void k_out(const float* __restrict__ hbuf,
                                             const float* __restrict__ W_out,
                                             const float* __restrict__ b_out,
                                             float* __restrict__ out) {
    __shared__ float W[VV * HH];
    __shared__ float bo[VV];
    __shared__ float stage[TT * VV];   // 256*37 floats = 37 KB
    const int b = blockIdx.x, t = threadIdx.x;
    for (int i = t; i < VV * HH; i += 256) W[i] = W_out[i];
    if (t < VV) bo[t] = b_out[t];
    __syncthreads();

    const float* hp = hbuf + ((size_t)b * TT + t) * HH;
    float hr[HH];
    #pragma unroll
    for (int k = 0; k < HH; ++k) hr[k] = hp[k];

    float z[VV];
    float m = -1e30f;
    #pragma unroll
    for (int v = 0; v < VV; ++v) {
        float s = bo[v];
        #pragma unroll
        for (int k = 0; k < HH; ++k) s += hr[k] * W[v * HH + k];
        z[v] = s;
        m = fmaxf(m, s);
    }
    float sum = 0.f;
    #pragma unroll
    for (int v = 0; v < VV; ++v) { z[v] = __expf(z[v] - m); sum += z[v]; }
    const float r = 1.f / sum;
    #pragma unroll
    for (int v = 0; v < VV; ++v) stage[t * VV + v] = z[v] * r;
    __syncthreads();

    float* ob = out + (size_t)b * TT * VV;
    for (int i = t; i < TT * VV; i += 256) ob[i] = stage[i];
}

// ---------------------------------------------------------------------------
// Workspace layout (floats):
//   feat  at 0          : 512*37      = 18,944
//   xproj at 32768      : 512*256*32  = 4,194,304   (128KB-aligned)
//   hbuf  at 4227072    : 512*256*8   = 1,048,576
// Total ~21.1 MB.
// ---------------------------------------------------------------------------
extern "C" void kernel_launch(void* const* d_in, const int* in_sizes, int n_in,
                              void* d_out, int out_size, void* d_ws, size_t ws_size,
                              hipStream_t stream) {
    const float* features = (const float*)d_in[0];
    const float* captions = (const float*)d_in[1];
    const float* W_in     = (const float*)d_in[2];
    const float* b_in     = (const float*)d_in[3];
    const float* W_ih     = (const float*)d_in[4];
    const float* W_hh     = (const float*)d_in[5];
    const float* b_ih     = (const float*)d_in[6];
    const float* b_hh     = (const float*)d_in[7];
    const float* W_out    = (const float*)d_in[8];
    const float* b_out    = (const float*)d_in[9];
    float* out = (float*)d_out;

    float* ws    = (float*)d_ws;
    float* feat  = ws;
    float* xproj = ws + 32768;
    float* hbuf  = ws + 32768 + 4194304;

    k_feat <<<BB,     256, 0, stream>>>(features, W_in, b_in, feat);
    k_xproj<<<BB,     256, 0, stream>>>(captions, W_ih, b_ih, b_hh, feat, xproj);
    k_lstm <<<BB / 8,  64, 0, stream>>>(W_hh, xproj, hbuf);
    k_out  <<<BB,     256, 0, stream>>>(hbuf, W_out, b_out, out);
}

// Round 2
// 240.926 us; speedup vs baseline: 1.1113x; 1.1113x over previous
//
#include <hip/hip_runtime.h>
#include <math.h>

// Problem constants
#define BB   512   // batch
#define TT   256   // timesteps
#define CNNC 512   // channels
#define VV   37    // vocab
#define HH   8     // hidden
#define G4   32    // 4*H
#define CH   32    // scan chunk length (timesteps); chunk = CH*G4*8 floats = 32 KB

// Async global->LDS copy, 16 B per lane. LDS dest = wave-uniform base + lane*16.
__device__ __forceinline__ void async_copy16(const float* g, float* l) {
    __builtin_amdgcn_global_load_lds(
        (__attribute__((address_space(1))) void*)g,
        (__attribute__((address_space(3))) void*)l, 16, 0, 0);
}

// ---------------------------------------------------------------------------
// Kernel 1: avg-pool(features) @ W_in.T + b_in -> feat[B][V]
// Stage the whole 100 KB feature block into LDS with coalesced float4 loads,
// then per-channel sums (stride-49 LDS reads: 49 mod 32 odd -> conflict-free),
// then 4 lanes per v reduce the 512-dot.
// ---------------------------------------------------------------------------
__global__ __launch_bounds__(256) void k_feat(const float* __restrict__ features,
                                              const float* __restrict__ W_in,
                                              const float* __restrict__ b_in,
                                              float* __restrict__ feat) {
    __shared__ __align__(16) float raw[CNNC * 49];   // 100352 B
    __shared__ float pooled[CNNC];
    const int b = blockIdx.x, tid = threadIdx.x;
    const float4* src = (const float4*)(features + (size_t)b * CNNC * 49);
    float4* dst = (float4*)raw;
    for (int i = tid; i < CNNC * 49 / 4; i += 256) dst[i] = src[i];
    __syncthreads();
    for (int c = tid; c < CNNC; c += 256) {
        const float* p = raw + c * 49;
        float s = 0.f;
        #pragma unroll
        for (int i = 0; i < 49; ++i) s += p[i];
        pooled[c] = s;
    }
    __syncthreads();
    const int v = tid >> 2, pp = tid & 3;
    if (v < VV) {
        const float* w = W_in + v * CNNC + pp * 128;
        const float* q = pooled + pp * 128;
        float s = 0.f;
        #pragma unroll 16
        for (int i = 0; i < 128; ++i) s += q[i] * w[i];
        s += __shfl_xor(s, 1);
        s += __shfl_xor(s, 2);
        if (pp == 0) feat[b * VV + v] = s * (1.f / 49.f) + b_in[v];
    }
}

// ---------------------------------------------------------------------------
// Kernel 2: xproj[bg][t][g][s] = x_t[b=bg*8+s] @ W_ih.T + (b_ih + b_hh)
// Layout chosen so k_lstm's chunk staging is a contiguous 32 KB copy and its
// LDS gate reads are 2-lanes/bank (free). Block = (bg, tile of 32 t).
// Thread (tl, s) computes one (b, t) row; results transposed through padded
// LDS (stride 260 -> 2-way conflicts only), written out as coalesced float4.
// ---------------------------------------------------------------------------
__global__ __launch_bounds__(256) void k_xproj(const float* __restrict__ captions,
                                               const float* __restrict__ W_ih,
                                               const float* __restrict__ b_ih,
                                               const float* __restrict__ b_hh,
                                               const float* __restrict__ feat,
                                               float* __restrict__ xproj) {
    __shared__ float W[G4 * VV];
    __shared__ float bias[G4];
    __shared__ __align__(16) float stage[32 * 260];
    const int bg = blockIdx.x, tile = blockIdx.y;
    const int tid = threadIdx.x;
    const int tl = tid >> 3, s = tid & 7;
    for (int i = tid; i < G4 * VV; i += 256) W[i] = W_ih[i];
    if (tid < G4) bias[tid] = b_ih[tid] + b_hh[tid];
    __syncthreads();

    const int t = tile * 32 + tl;
    const int b = bg * 8 + s;
    const float* x = (t == 0) ? (feat + b * VV)
                              : (captions + ((size_t)b * TT + (t - 1)) * VV);
    float xr[VV];
    #pragma unroll
    for (int v = 0; v < VV; ++v) xr[v] = x[v];

    float acc[G4];
    #pragma unroll
    for (int g = 0; g < G4; ++g) acc[g] = bias[g];
    #pragma unroll
    for (int v = 0; v < VV; ++v) {
        const float xv = xr[v];
        #pragma unroll
        for (int g = 0; g < G4; ++g) acc[g] += xv * W[g * VV + v];
    }
    #pragma unroll
    for (int g = 0; g < G4; ++g) stage[tl * 260 + g * 8 + s] = acc[g];
    __syncthreads();

    float* chunk = xproj + ((size_t)bg * TT + tile * 32) * (G4 * 8);
    for (int f4 = tid; f4 < 2048; f4 += 256) {
        const int row = f4 >> 6, off4 = f4 & 63;
        float4 val = *(const float4*)&stage[row * 260 + off4 * 4];
        *((float4*)chunk + f4) = val;
    }
}

// ---------------------------------------------------------------------------
// Kernel 3: the sequential scan. 64 blocks x 1 wave; lane = s*8+j owns hidden
// unit j of sequence bg*8+s. xproj chunks (32 steps = 32 KB) are staged into
// double-buffered LDS via global_load_lds one chunk ahead -> global latency
// off the recurrence chain. h broadcast within the 8-lane group via __shfl.
// ---------------------------------------------------------------------------
__global__ __launch_bounds__(64) void k_lstm(const float* __restrict__ W_hh,
                                             const float* __restrict__ xproj,
                                             float* __restrict__ hbuf) {
    __shared__ __align__(16) float buf[2][CH * G4 * 8];   // 2 x 32 KB
    const int lane = threadIdx.x;
    const int s = lane >> 3, j = lane & 7;
    const int bg = blockIdx.x;

    float wi[HH], wf[HH], wg[HH], wo[HH];
    #pragma unroll
    for (int k = 0; k < HH; ++k) {
        wi[k] = W_hh[(0 * HH + j) * HH + k];
        wf[k] = W_hh[(1 * HH + j) * HH + k];
        wg[k] = W_hh[(2 * HH + j) * HH + k];
        wo[k] = W_hh[(3 * HH + j) * HH + k];
    }

    const float* xp = xproj + (size_t)bg * TT * G4 * 8;
    float* hp = hbuf + ((size_t)(bg * 8 + s) * TT) * HH + j;

    // stage chunk 0 (32 calls x 64 lanes x 16 B = 32 KB, contiguous mirror)
    #pragma unroll
    for (int it = 0; it < 32; ++it)
        async_copy16(xp + (it * 64 + lane) * 4, &buf[0][it * 256]);

    float h = 0.f, c = 0.f;
    for (int ck = 0; ck < TT / CH; ++ck) {
        const int pb = ck & 1;
        asm volatile("s_waitcnt vmcnt(0)" ::: "memory");   // chunk ck resident
        if (ck + 1 < TT / CH) {
            const float* src = xp + (size_t)(ck + 1) * (CH * G4 * 8);
            #pragma unroll
            for (int it = 0; it < 32; ++it)
                async_copy16(src + (it * 64 + lane) * 4, &buf[pb ^ 1][it * 256]);
        }
        const float* xb = &buf[pb][j * 8 + s];
        #pragma unroll 4
        for (int tl = 0; tl < CH; ++tl) {
            const float* xq = xb + tl * 256;        // [t][g][s]: g=j,8+j,16+j,24+j
            float pi = xq[0], pf = xq[64], pg = xq[128], po = xq[192];
            float ha[HH];
            #pragma unroll
            for (int k = 0; k < HH; ++k) ha[k] = __shfl(h, (s << 3) + k);
            #pragma unroll
            for (int k = 0; k < HH; ++k) {
                pi += wi[k] * ha[k];
                pf += wf[k] * ha[k];
                pg += wg[k] * ha[k];
                po += wo[k] * ha[k];
            }
            const float ig = 1.f / (1.f + __expf(-pi));
            const float fg = 1.f / (1.f + __expf(-pf));
            const float gg = 2.f / (1.f + __expf(-2.f * pg)) - 1.f;   // tanh
            const float og = 1.f / (1.f + __expf(-po));
            c = fg * c + ig * gg;
            const float th = 2.f / (1.f + __expf(-2.f * c)) - 1.f;    // tanh
            h = og * th;
            hp[(ck * CH + tl) * HH] = h;            // fire-and-forget store
        }
    }
}

// ---------------------------------------------------------------------------
// Kernel 4: out[b][t][:] = softmax(h_t @ W_out.T + b_out). One block per b,
// thread t = one row; float4 hbuf reads; LDS-staged, float4-coalesced writes.
// Dominant dispatch: ~190 MB of HBM writes.
// ---------------------------------------------------------------------------
__global__ __launch_bounds__(256) void k_out(const float* __restrict__ hbuf,
                                             const float* __restrict__ W_out,
                                             const float* __restrict__ b_out,
                                             float* __restrict__ out) {
    __shared__ float W[VV * HH];
    __shared__ float bo[VV];
    __shared__ __align__(16) float stage[TT * VV];   // 37 KB
    const int b = blockIdx.x, t = threadIdx.x;
    for (int i = t; i < VV * HH; i += 256) W[i] = W_out[i];
    if (t < VV) bo[t] = b_out[t];
    __syncthreads();

    const float4* hp = (const float4*)(hbuf + ((size_t)b * TT + t) * HH);
    const float4 h0 = hp[0], h1 = hp[1];
    const float hr[HH] = {h0.x, h0.y, h0.z, h0.w, h1.x, h1.y, h1.z, h1.w};

    float z[VV];
    float m = -1e30f;
    #pragma unroll
    for (int v = 0; v < VV; ++v) {
        float sv = bo[v];
        #pragma unroll
        for (int k = 0; k < HH; ++k) sv += hr[k] * W[v * HH + k];
        z[v] = sv;
        m = fmaxf(m, sv);
    }
    float sum = 0.f;
    #pragma unroll
    for (int v = 0; v < VV; ++v) { z[v] = __expf(z[v] - m); sum += z[v]; }
    const float r = 1.f / sum;
    #pragma unroll
    for (int v = 0; v < VV; ++v) stage[t * VV + v] = z[v] * r;
    __syncthreads();

    float4* ob = (float4*)(out + (size_t)b * TT * VV);
    const float4* sg = (const float4*)stage;
    for (int i = t; i < TT * VV / 4; i += 256) ob[i] = sg[i];
}

// ---------------------------------------------------------------------------
// Workspace (floats): feat@0 (18,944) | xproj@32768 (4,194,304, [bg][t][g][s])
//                     hbuf@4227072 (1,048,576, [b][t][j])
// ---------------------------------------------------------------------------
extern "C" void kernel_launch(void* const* d_in, const int* in_sizes, int n_in,
                              void* d_out, int out_size, void* d_ws, size_t ws_size,
                              hipStream_t stream) {
    const float* features = (const float*)d_in[0];
    const float* captions = (const float*)d_in[1];
    const float* W_in     = (const float*)d_in[2];
    const float* b_in     = (const float*)d_in[3];
    const float* W_ih     = (const float*)d_in[4];
    const float* W_hh     = (const float*)d_in[5];
    const float* b_ih     = (const float*)d_in[6];
    const float* b_hh     = (const float*)d_in[7];
    const float* W_out    = (const float*)d_in[8];
    const float* b_out    = (const float*)d_in[9];
    float* out = (float*)d_out;

    float* ws    = (float*)d_ws;
    float* feat  = ws;
    float* xproj = ws + 32768;
    float* hbuf  = ws + 32768 + 4194304;

    k_feat <<<BB,          256, 0, stream>>>(features, W_in, b_in, feat);
    k_xproj<<<dim3(64, 8), 256, 0, stream>>>(captions, W_ih, b_ih, b_hh, feat, xproj);
    k_lstm <<<BB / 8,       64, 0, stream>>>(W_hh, xproj, hbuf);
    k_out  <<<BB,          256, 0, stream>>>(hbuf, W_out, b_out, out);
}

// Round 3
// 236.468 us; speedup vs baseline: 1.1323x; 1.0189x over previous
//
#include <hip/hip_runtime.h>
#include <math.h>

// Problem constants
#define BB   512   // batch
#define TT   256   // timesteps
#define CNNC 512   // channels
#define VV   37    // vocab
#define HH   8     // hidden
#define G4   32    // 4*H
#define CH   32    // scan chunk length (timesteps); chunk = CH*G4*8 floats = 32 KB

// Async global->LDS copy, 16 B per lane. LDS dest = wave-uniform base + lane*16.
__device__ __forceinline__ void async_copy16(const float* g, float* l) {
    __builtin_amdgcn_global_load_lds(
        (__attribute__((address_space(1))) void*)g,
        (__attribute__((address_space(3))) void*)l, 16, 0, 0);
}

// DPP cross-lane mov: pure VALU (~4-8 cyc) vs ds_bpermute (~120 cyc).
// ctrl: quad_perm 0x00-0xFF; row_mirror 0x140; row_half_mirror 0x141.
template <int CTRL>
__device__ __forceinline__ float dpp_f(float x) {
    int r = __builtin_amdgcn_update_dpp(0, __float_as_int(x), CTRL, 0xF, 0xF, true);
    return __int_as_float(r);
}

// ---------------------------------------------------------------------------
// Kernel 1: avg-pool(features) @ W_in.T + b_in -> feat[B][V]
// ---------------------------------------------------------------------------
__global__ __launch_bounds__(256) void k_feat(const float* __restrict__ features,
                                              const float* __restrict__ W_in,
                                              const float* __restrict__ b_in,
                                              float* __restrict__ feat) {
    __shared__ __align__(16) float raw[CNNC * 49];   // 100352 B
    __shared__ float pooled[CNNC];
    const int b = blockIdx.x, tid = threadIdx.x;
    const float4* src = (const float4*)(features + (size_t)b * CNNC * 49);
    float4* dst = (float4*)raw;
    for (int i = tid; i < CNNC * 49 / 4; i += 256) dst[i] = src[i];
    __syncthreads();
    for (int c = tid; c < CNNC; c += 256) {
        const float* p = raw + c * 49;
        float s = 0.f;
        #pragma unroll
        for (int i = 0; i < 49; ++i) s += p[i];
        pooled[c] = s;
    }
    __syncthreads();
    const int v = tid >> 2, pp = tid & 3;
    if (v < VV) {
        const float* w = W_in + v * CNNC + pp * 128;
        const float* q = pooled + pp * 128;
        float s = 0.f;
        #pragma unroll 16
        for (int i = 0; i < 128; ++i) s += q[i] * w[i];
        s += __shfl_xor(s, 1);
        s += __shfl_xor(s, 2);
        if (pp == 0) feat[b * VV + v] = s * (1.f / 49.f) + b_in[v];
    }
}

// ---------------------------------------------------------------------------
// Kernel 2: xproj[bg][t][g][s] = x_t[b=bg*8+s] @ W_ih.T + (b_ih + b_hh)
// Captions staged through LDS with coalesced dword loads (8 contiguous
// 4736 B runs per block); compute reads LDS (stride 1185 -> <=2-way banks).
// Output transposed through padded LDS, written as coalesced float4.
// ---------------------------------------------------------------------------
#define CSTR 1185   // caption stage stride (1184 + 1, odd -> bank spread)
__global__ __launch_bounds__(256) void k_xproj(const float* __restrict__ captions,
                                               const float* __restrict__ W_ih,
                                               const float* __restrict__ b_ih,
                                               const float* __restrict__ b_hh,
                                               const float* __restrict__ feat,
                                               float* __restrict__ xproj) {
    __shared__ float W[G4 * VV];
    __shared__ float bias[G4];
    __shared__ float cap[8 * CSTR];                  // 8 b x 32 rows x 37
    __shared__ __align__(16) float stage[32 * 260];
    const int bg = blockIdx.x, tile = blockIdx.y;
    const int tid = threadIdx.x;
    const int tl = tid >> 3, s = tid & 7;
    for (int i = tid; i < G4 * VV; i += 256) W[i] = W_ih[i];
    if (tid < G4) bias[tid] = b_ih[tid] + b_hh[tid];

    // stage rows [start, start+32) of captions for the block's 8 sequences
    const int t0 = tile * 32;
    const int start = (tile == 0) ? 0 : t0 - 1;
    for (int i = tid; i < 8 * 1184; i += 256) {
        const int s2 = i / 1184;                      // const-div -> mul/shift
        const int off = i - s2 * 1184;
        cap[s2 * CSTR + off] =
            captions[((size_t)(bg * 8 + s2) * TT + start) * VV + off];
    }
    __syncthreads();

    const int b = bg * 8 + s;
    const int lr = (tile == 0) ? tl - 1 : tl;         // local staged row of x
    const float* x = (tile == 0 && tl == 0) ? (feat + b * VV)
                                            : &cap[s * CSTR + lr * VV];
    float xr[VV];
    #pragma unroll
    for (int v = 0; v < VV; ++v) xr[v] = x[v];

    float acc[G4];
    #pragma unroll
    for (int g = 0; g < G4; ++g) acc[g] = bias[g];
    #pragma unroll
    for (int v = 0; v < VV; ++v) {
        const float xv = xr[v];
        #pragma unroll
        for (int g = 0; g < G4; ++g) acc[g] += xv * W[g * VV + v];
    }
    #pragma unroll
    for (int g = 0; g < G4; ++g) stage[tl * 260 + g * 8 + s] = acc[g];
    __syncthreads();

    float* chunk = xproj + ((size_t)bg * TT + t0) * (G4 * 8);
    for (int f4 = tid; f4 < 2048; f4 += 256) {
        const int row = f4 >> 6, off4 = f4 & 63;
        float4 val = *(const float4*)&stage[row * 260 + off4 * 4];
        *((float4*)chunk + f4) = val;
    }
}

// ---------------------------------------------------------------------------
// Kernel 3: the sequential scan. 64 blocks x 1 wave; lane = s*8+j owns hidden
// unit j of sequence bg*8+s. xproj chunks double-buffered in LDS via
// global_load_lds. h all-to-all within each 8-lane group done with 7 DPP
// movs (VALU latency) instead of ds_bpermute -- the R2 chain bottleneck.
// Weights pre-permuted so ha[m] = h_{j^m} pairs with w[m] = W[j][j^m].
// ---------------------------------------------------------------------------
__global__ __launch_bounds__(64) void k_lstm(const float* __restrict__ W_hh,
                                             const float* __restrict__ xproj,
                                             float* __restrict__ hbuf) {
    __shared__ __align__(16) float buf[2][CH * G4 * 8];   // 2 x 32 KB
    const int lane = threadIdx.x;
    const int s = lane >> 3, j = lane & 7;
    const int bg = blockIdx.x;

    float wi[HH], wf[HH], wg[HH], wo[HH];
    #pragma unroll
    for (int m = 0; m < HH; ++m) {
        const int k = j ^ m;                           // xor-permuted weight order
        wi[m] = W_hh[(0 * HH + j) * HH + k];
        wf[m] = W_hh[(1 * HH + j) * HH + k];
        wg[m] = W_hh[(2 * HH + j) * HH + k];
        wo[m] = W_hh[(3 * HH + j) * HH + k];
    }

    const float* xp = xproj + (size_t)bg * TT * G4 * 8;
    float* hp = hbuf + ((size_t)(bg * 8 + s) * TT) * HH + j;

    // stage chunk 0 (32 calls x 64 lanes x 16 B = 32 KB, contiguous mirror)
    #pragma unroll
    for (int it = 0; it < 32; ++it)
        async_copy16(xp + (it * 64 + lane) * 4, &buf[0][it * 256]);

    float h = 0.f, c = 0.f;
    for (int ck = 0; ck < TT / CH; ++ck) {
        const int pb = ck & 1;
        asm volatile("s_waitcnt vmcnt(0)" ::: "memory");   // chunk ck resident
        if (ck + 1 < TT / CH) {
            const float* src = xp + (size_t)(ck + 1) * (CH * G4 * 8);
            #pragma unroll
            for (int it = 0; it < 32; ++it)
                async_copy16(src + (it * 64 + lane) * 4, &buf[pb ^ 1][it * 256]);
        }
        const float* xb = &buf[pb][j * 8 + s];
        #pragma unroll 4
        for (int tl = 0; tl < CH; ++tl) {
            const float* xq = xb + tl * 256;        // [t][g][s]: g=j,8+j,16+j,24+j
            float pi = xq[0], pf = xq[64], pg = xq[128], po = xq[192];

            float ha[HH];                            // ha[m] = h_{j^m}
            ha[0] = h;
            ha[1] = dpp_f<0xB1>(h);                  // quad_perm xor1
            ha[2] = dpp_f<0x4E>(h);                  // quad_perm xor2
            ha[3] = dpp_f<0x1B>(h);                  // quad_perm xor3
            ha[7] = dpp_f<0x141>(h);                 // row_half_mirror = xor7
            ha[6] = dpp_f<0xB1>(ha[7]);              // xor6
            ha[5] = dpp_f<0x4E>(ha[7]);              // xor5
            ha[4] = dpp_f<0x1B>(ha[7]);              // xor4

            #pragma unroll
            for (int m = 0; m < HH; ++m) {
                pi += wi[m] * ha[m];
                pf += wf[m] * ha[m];
                pg += wg[m] * ha[m];
                po += wo[m] * ha[m];
            }
            const float ig = 1.f / (1.f + __expf(-pi));
            const float fg = 1.f / (1.f + __expf(-pf));
            const float gg = 2.f / (1.f + __expf(-2.f * pg)) - 1.f;   // tanh
            const float og = 1.f / (1.f + __expf(-po));
            c = fg * c + ig * gg;
            const float th = 2.f / (1.f + __expf(-2.f * c)) - 1.f;    // tanh
            h = og * th;
            hp[(ck * CH + tl) * HH] = h;            // fire-and-forget store
        }
    }
}

// ---------------------------------------------------------------------------
// Kernel 4: out[b][t][:] = softmax(h_t @ W_out.T + b_out). One block per b,
// thread t = one row; float4 hbuf reads; LDS-staged, float4-coalesced writes.
// Dominant dispatch: ~190 MB of HBM writes.
// ---------------------------------------------------------------------------
__global__ __launch_bounds__(256) void k_out(const float* __restrict__ hbuf,
                                             const float* __restrict__ W_out,
                                             const float* __restrict__ b_out,
                                             float* __restrict__ out) {
    __shared__ float W[VV * HH];
    __shared__ float bo[VV];
    __shared__ __align__(16) float stage[TT * VV];   // 37 KB
    const int b = blockIdx.x, t = threadIdx.x;
    for (int i = t; i < VV * HH; i += 256) W[i] = W_out[i];
    if (t < VV) bo[t] = b_out[t];
    __syncthreads();

    const float4* hp = (const float4*)(hbuf + ((size_t)b * TT + t) * HH);
    const float4 h0 = hp[0], h1 = hp[1];
    const float hr[HH] = {h0.x, h0.y, h0.z, h0.w, h1.x, h1.y, h1.z, h1.w};

    float z[VV];
    float m = -1e30f;
    #pragma unroll
    for (int v = 0; v < VV; ++v) {
        float sv = bo[v];
        #pragma unroll
        for (int k = 0; k < HH; ++k) sv += hr[k] * W[v * HH + k];
        z[v] = sv;
        m = fmaxf(m, sv);
    }
    float sum = 0.f;
    #pragma unroll
    for (int v = 0; v < VV; ++v) { z[v] = __expf(z[v] - m); sum += z[v]; }
    const float r = 1.f / sum;
    #pragma unroll
    for (int v = 0; v < VV; ++v) stage[t * VV + v] = z[v] * r;
    __syncthreads();

    float4* ob = (float4*)(out + (size_t)b * TT * VV);
    const float4* sg = (const float4*)stage;
    for (int i = t; i < TT * VV / 4; i += 256) ob[i] = sg[i];
}

// ---------------------------------------------------------------------------
// Workspace (floats): feat@0 (18,944) | xproj@32768 (4,194,304, [bg][t][g][s])
//                     hbuf@4227072 (1,048,576, [b][t][j])
// ---------------------------------------------------------------------------
extern "C" void kernel_launch(void* const* d_in, const int* in_sizes, int n_in,
                              void* d_out, int out_size, void* d_ws, size_t ws_size,
                              hipStream_t stream) {
    const float* features = (const float*)d_in[0];
    const float* captions = (const float*)d_in[1];
    const float* W_in     = (const float*)d_in[2];
    const float* b_in     = (const float*)d_in[3];
    const float* W_ih     = (const float*)d_in[4];
    const float* W_hh     = (const float*)d_in[5];
    const float* b_ih     = (const float*)d_in[6];
    const float* b_hh     = (const float*)d_in[7];
    const float* W_out    = (const float*)d_in[8];
    const float* b_out    = (const float*)d_in[9];
    float* out = (float*)d_out;

    float* ws    = (float*)d_ws;
    float* feat  = ws;
    float* xproj = ws + 32768;
    float* hbuf  = ws + 32768 + 4194304;

    k_feat <<<BB,          256, 0, stream>>>(features, W_in, b_in, feat);
    k_xproj<<<dim3(64, 8), 256, 0, stream>>>(captions, W_ih, b_ih, b_hh, feat, xproj);
    k_lstm <<<BB / 8,       64, 0, stream>>>(W_hh, xproj, hbuf);
    k_out  <<<BB,          256, 0, stream>>>(hbuf, W_out, b_out, out);
}

// Round 4
// 209.500 us; speedup vs baseline: 1.2780x; 1.1287x over previous
//
#include <hip/hip_runtime.h>
#include <math.h>

// Problem constants
#define BB   512   // batch
#define TT   256   // timesteps
#define CNNC 512   // channels
#define VV   37    // vocab
#define HH   8     // hidden
#define G4   32    // 4*H
#define CH   32    // scan chunk length (timesteps); chunk = CH*G4*8 floats = 32 KB

#define L2E 1.4426950408889634f

// Async global->LDS copy, 16 B per lane. LDS dest = wave-uniform base + lane*16.
__device__ __forceinline__ void async_copy16(const float* g, float* l) {
    __builtin_amdgcn_global_load_lds(
        (__attribute__((address_space(1))) void*)g,
        (__attribute__((address_space(3))) void*)l, 16, 0, 0);
}

// DPP cross-lane mov: pure VALU latency vs ~120cyc ds_bpermute.
template <int CTRL>
__device__ __forceinline__ float dpp_f(float x) {
    int r = __builtin_amdgcn_update_dpp(0, __float_as_int(x), CTRL, 0xF, 0xF, true);
    return __int_as_float(r);
}

// raw v_rcp_f32 (1 ulp) -- avoids the 6-op IEEE divide expansion
__device__ __forceinline__ float rcp_f(float x) { return __builtin_amdgcn_rcpf(x); }
// raw v_exp_f32 (2^x)
__device__ __forceinline__ float exp2_f(float x) { return __builtin_amdgcn_exp2f(x); }

// ---------------------------------------------------------------------------
// Kernel 1: avg-pool(features) @ W_in.T partial -> featp[half][B][V]
// Split per-b work into 2 half-channel blocks: 50 KB LDS -> 3 blocks/CU
// (was 100 KB -> 1 block/CU). b_in added in half 0 only; k_xproj sums halves.
// ---------------------------------------------------------------------------
__global__ __launch_bounds__(256) void k_feat(const float* __restrict__ features,
                                              const float* __restrict__ W_in,
                                              const float* __restrict__ b_in,
                                              float* __restrict__ featp) {
    __shared__ __align__(16) float raw[256 * 49];    // 50176 B
    __shared__ float pooled[256];
    const int b = blockIdx.x, half = blockIdx.y, tid = threadIdx.x;
    const float4* src =
        (const float4*)(features + (size_t)b * CNNC * 49 + half * (256 * 49));
    float4* dst = (float4*)raw;
    for (int i = tid; i < 256 * 49 / 4; i += 256) dst[i] = src[i];
    __syncthreads();
    {
        const float* p = raw + tid * 49;
        float s = 0.f;
        #pragma unroll
        for (int i = 0; i < 49; ++i) s += p[i];
        pooled[tid] = s;
    }
    __syncthreads();
    const int v = tid >> 2, pp = tid & 3;
    if (v < VV) {
        const float* w = W_in + v * CNNC + half * 256 + pp * 64;
        const float* q = pooled + pp * 64;
        float s = 0.f;
        #pragma unroll 16
        for (int i = 0; i < 64; ++i) s += q[i] * w[i];
        s += __shfl_xor(s, 1);
        s += __shfl_xor(s, 2);
        if (pp == 0)
            featp[(half * BB + b) * VV + v] =
                s * (1.f / 49.f) + (half == 0 ? b_in[v] : 0.f);
    }
}

// ---------------------------------------------------------------------------
// Kernel 2: xproj[bg][t][g][s] = -(x_t @ W_ih.T + b_ih + b_hh) * scale_g
//   scale_g = L2E for gates i,f,o and 2*L2E for gate g, NEGATED, so k_lstm's
//   sigmoid/tanh are pure rcp(1+exp2(p)) with zero muls on the chain.
// ---------------------------------------------------------------------------
#define CSTR 1185   // caption stage stride (odd -> bank spread)
__global__ __launch_bounds__(256) void k_xproj(const float* __restrict__ captions,
                                               const float* __restrict__ W_ih,
                                               const float* __restrict__ b_ih,
                                               const float* __restrict__ b_hh,
                                               const float* __restrict__ featp,
                                               float* __restrict__ xproj) {
    __shared__ float W[G4 * VV];
    __shared__ float bias[G4];
    __shared__ float cap[8 * CSTR];                  // 8 b x 32 rows x 37
    __shared__ __align__(16) float stage[32 * 260];
    const int bg = blockIdx.x, tile = blockIdx.y;
    const int tid = threadIdx.x;
    const int tl = tid >> 3, s = tid & 7;
    for (int i = tid; i < G4 * VV; i += 256) W[i] = W_ih[i];
    if (tid < G4) bias[tid] = b_ih[tid] + b_hh[tid];

    // stage rows [start, start+32) of captions for the block's 8 sequences
    const int t0 = tile * 32;
    const int start = (tile == 0) ? 0 : t0 - 1;
    for (int i = tid; i < 8 * 1184; i += 256) {
        const int s2 = i / 1184;                      // const-div -> mul/shift
        const int off = i - s2 * 1184;
        cap[s2 * CSTR + off] =
            captions[((size_t)(bg * 8 + s2) * TT + start) * VV + off];
    }
    __syncthreads();

    const int b = bg * 8 + s;
    const int lr = (tile == 0) ? tl - 1 : tl;         // local staged row of x
    float xr[VV];
    if (tile == 0 && tl == 0) {
        #pragma unroll
        for (int v = 0; v < VV; ++v)
            xr[v] = featp[b * VV + v] + featp[(BB + b) * VV + v];
    } else {
        const float* x = &cap[s * CSTR + lr * VV];
        #pragma unroll
        for (int v = 0; v < VV; ++v) xr[v] = x[v];
    }

    float acc[G4];
    #pragma unroll
    for (int g = 0; g < G4; ++g) acc[g] = bias[g];
    #pragma unroll
    for (int v = 0; v < VV; ++v) {
        const float xv = xr[v];
        #pragma unroll
        for (int g = 0; g < G4; ++g) acc[g] += xv * W[g * VV + v];
    }
    #pragma unroll
    for (int g = 0; g < G4; ++g) {
        const float sc = (g >= 16 && g < 24) ? (-2.f * L2E) : (-L2E);
        stage[tl * 260 + g * 8 + s] = acc[g] * sc;
    }
    __syncthreads();

    float* chunk = xproj + ((size_t)bg * TT + t0) * (G4 * 8);
    for (int f4 = tid; f4 < 2048; f4 += 256) {
        const int row = f4 >> 6, off4 = f4 & 63;
        float4 val = *(const float4*)&stage[row * 260 + off4 * 4];
        *((float4*)chunk + f4) = val;
    }
}

// ---------------------------------------------------------------------------
// Kernel 3: the sequential scan. 64 blocks x 1 wave; lane = s*8+j owns hidden
// unit j of sequence bg*8+s. Chain surgery vs R3:
//   - gate pre-activations arrive pre-negated & pre-log2e-scaled -> each
//     sigmoid/tanh is rcp(1+exp2(p)): v_exp + v_add + v_rcp, no muls/divides
//   - W_hh register copies likewise pre-scaled/negated
//   - the 4 LDS gate reads are software-pipelined one step ahead into regs
//     (LDS padded so the tl=31 over-read is harmless garbage, discarded)
// ---------------------------------------------------------------------------
__global__ __launch_bounds__(64) void k_lstm(const float* __restrict__ W_hh,
                                             const float* __restrict__ xproj,
                                             float* __restrict__ hbuf) {
    __shared__ __align__(16) float buf0[2 * CH * 256 + 256];   // 2x32KB + pad
    const int lane = threadIdx.x;
    const int s = lane >> 3, j = lane & 7;
    const int bg = blockIdx.x;

    float wi[HH], wf[HH], wg[HH], wo[HH];
    #pragma unroll
    for (int m = 0; m < HH; ++m) {
        const int k = j ^ m;                           // xor-permuted weight order
        wi[m] = -L2E * W_hh[(0 * HH + j) * HH + k];
        wf[m] = -L2E * W_hh[(1 * HH + j) * HH + k];
        wg[m] = -2.f * L2E * W_hh[(2 * HH + j) * HH + k];
        wo[m] = -L2E * W_hh[(3 * HH + j) * HH + k];
    }

    const float* xp = xproj + (size_t)bg * TT * G4 * 8;
    float* hp = hbuf + ((size_t)(bg * 8 + s) * TT) * HH + j;

    // stage chunk 0 (32 calls x 64 lanes x 16 B = 32 KB, contiguous mirror)
    #pragma unroll
    for (int it = 0; it < 32; ++it)
        async_copy16(xp + (it * 64 + lane) * 4, &buf0[it * 256]);

    float h = 0.f, c = 0.f;
    for (int ck = 0; ck < TT / CH; ++ck) {
        const int pb = ck & 1;
        asm volatile("s_waitcnt vmcnt(0)" ::: "memory");   // chunk ck resident
        if (ck + 1 < TT / CH) {
            const float* src = xp + (size_t)(ck + 1) * (CH * G4 * 8);
            float* db = &buf0[(pb ^ 1) * (CH * 256)];
            #pragma unroll
            for (int it = 0; it < 32; ++it)
                async_copy16(src + (it * 64 + lane) * 4, &db[it * 256]);
        }
        const float* xb = &buf0[pb * (CH * 256) + j * 8 + s];
        float p0 = xb[0], p1 = xb[64], p2 = xb[128], p3 = xb[192];
        #pragma unroll 4
        for (int tl = 0; tl < CH; ++tl) {
            // prefetch next step's gate inputs (tl=31 reads pad: discarded)
            const float* nq = xb + (tl + 1) * 256;
            const float n0 = nq[0], n1 = nq[64], n2 = nq[128], n3 = nq[192];

            float ha[HH];                            // ha[m] = h_{j^m}
            ha[0] = h;
            ha[1] = dpp_f<0xB1>(h);                  // xor1
            ha[2] = dpp_f<0x4E>(h);                  // xor2
            ha[3] = dpp_f<0x1B>(h);                  // xor3
            ha[7] = dpp_f<0x141>(h);                 // row_half_mirror = xor7
            ha[6] = dpp_f<0xB1>(ha[7]);              // xor6
            ha[5] = dpp_f<0x4E>(ha[7]);              // xor5
            ha[4] = dpp_f<0x1B>(ha[7]);              // xor4

            float npi = p0, npf = p1, npg = p2, npo = p3;
            #pragma unroll
            for (int m = 0; m < HH; ++m) {
                npi += wi[m] * ha[m];
                npf += wf[m] * ha[m];
                npg += wg[m] * ha[m];
                npo += wo[m] * ha[m];
            }
            // np* = -log2e-scaled pre-activations
            const float ig = rcp_f(1.f + exp2_f(npi));
            const float fg = rcp_f(1.f + exp2_f(npf));
            const float gg = fmaf(2.f, rcp_f(1.f + exp2_f(npg)), -1.f);
            const float og = rcp_f(1.f + exp2_f(npo));
            c = fmaf(fg, c, ig * gg);
            const float th =
                fmaf(2.f, rcp_f(1.f + exp2_f(c * (-2.f * L2E))), -1.f);
            h = og * th;
            hp[(ck * CH + tl) * HH] = h;            // fire-and-forget store
            p0 = n0; p1 = n1; p2 = n2; p3 = n3;
        }
    }
}

// ---------------------------------------------------------------------------
// Kernel 4: out[b][t][:] = softmax(h_t @ W_out.T + b_out). One block per b,
// thread t = one row; float4 hbuf reads; LDS-staged, float4-coalesced writes.
// Dominant HBM dispatch: ~190 MB of writes.
// ---------------------------------------------------------------------------
__global__ __launch_bounds__(256) void k_out(const float* __restrict__ hbuf,
                                             const float* __restrict__ W_out,
                                             const float* __restrict__ b_out,
                                             float* __restrict__ out) {
    __shared__ float W[VV * HH];
    __shared__ float bo[VV];
    __shared__ __align__(16) float stage[TT * VV];   // 37 KB
    const int b = blockIdx.x, t = threadIdx.x;
    for (int i = t; i < VV * HH; i += 256) W[i] = W_out[i];
    if (t < VV) bo[t] = b_out[t];
    __syncthreads();

    const float4* hp = (const float4*)(hbuf + ((size_t)b * TT + t) * HH);
    const float4 h0 = hp[0], h1 = hp[1];
    const float hr[HH] = {h0.x, h0.y, h0.z, h0.w, h1.x, h1.y, h1.z, h1.w};

    float z[VV];
    float m = -1e30f;
    #pragma unroll
    for (int v = 0; v < VV; ++v) {
        float sv = bo[v];
        #pragma unroll
        for (int k = 0; k < HH; ++k) sv += hr[k] * W[v * HH + k];
        z[v] = sv;
        m = fmaxf(m, sv);
    }
    float sum = 0.f;
    #pragma unroll
    for (int v = 0; v < VV; ++v) {
        z[v] = exp2_f((z[v] - m) * L2E);
        sum += z[v];
    }
    const float r = rcp_f(sum);
    #pragma unroll
    for (int v = 0; v < VV; ++v) stage[t * VV + v] = z[v] * r;
    __syncthreads();

    float4* ob = (float4*)(out + (size_t)b * TT * VV);
    const float4* sg = (const float4*)stage;
    for (int i = t; i < TT * VV / 4; i += 256) ob[i] = sg[i];
}

// ---------------------------------------------------------------------------
// Workspace (floats): featp@0 (2*512*37=37,888) | xproj@40960 (4,194,304)
//                     hbuf@4235264 (1,048,576)   -- total ~21.1 MB
// ---------------------------------------------------------------------------
extern "C" void kernel_launch(void* const* d_in, const int* in_sizes, int n_in,
                              void* d_out, int out_size, void* d_ws, size_t ws_size,
                              hipStream_t stream) {
    const float* features = (const float*)d_in[0];
    const float* captions = (const float*)d_in[1];
    const float* W_in     = (const float*)d_in[2];
    const float* b_in     = (const float*)d_in[3];
    const float* W_ih     = (const float*)d_in[4];
    const float* W_hh     = (const float*)d_in[5];
    const float* b_ih     = (const float*)d_in[6];
    const float* b_hh     = (const float*)d_in[7];
    const float* W_out    = (const float*)d_in[8];
    const float* b_out    = (const float*)d_in[9];
    float* out = (float*)d_out;

    float* ws    = (float*)d_ws;
    float* featp = ws;
    float* xproj = ws + 40960;
    float* hbuf  = ws + 40960 + 4194304;

    k_feat <<<dim3(BB, 2), 256, 0, stream>>>(features, W_in, b_in, featp);
    k_xproj<<<dim3(64, 8), 256, 0, stream>>>(captions, W_ih, b_ih, b_hh, featp, xproj);
    k_lstm <<<BB / 8,       64, 0, stream>>>(W_hh, xproj, hbuf);
    k_out  <<<BB,          256, 0, stream>>>(hbuf, W_out, b_out, out);
}